// Round 1
// baseline (4397.311 us; speedup 1.0000x reference)
//
#include <hip/hip_runtime.h>

#define E_TRIP 500000
#define EPAD   500224              // multiple of 256; >= c0_pad + c1 always
#define NTILE64 (EPAD/64)          // 7816
#define NBLK256 (EPAD/256)         // 1954
#define NN 100000
#define EPSF 1e-5f

typedef _Float16 f16;
typedef _Float16 f16x8 __attribute__((ext_vector_type(8)));
typedef float f32x4 __attribute__((ext_vector_type(4)));

// ---------------- prep ----------------
__global__ __launch_bounds__(256) void k_count(const int* __restrict__ ewf,
    const int* __restrict__ exij, const int* __restrict__ exjk,
    unsigned char* __restrict__ biedge, int* __restrict__ sc)
{
  int e = blockIdx.x*256 + threadIdx.x;
  bool active = e < E_TRIP;
  int b = 0;
  if (active) {
    int fij = ewf[exij[e]];
    int fjk = ewf[exjk[e]];
    b = (fij == fjk) ? 0 : 1;
    biedge[e] = (unsigned char)b;
  }
  unsigned long long m0 = __ballot(active && b==0);
  unsigned long long m1 = __ballot(active && b==1);
  int lane = threadIdx.x & 63;
  if (m0 && lane == (__ffsll((long long)m0)-1)) atomicAdd(&sc[0], (int)__popcll(m0));
  if (m1 && lane == (__ffsll((long long)m1)-1)) atomicAdd(&sc[1], (int)__popcll(m1));
}

__global__ void k_scal(int* sc)
{
  int c0 = sc[0], c1 = sc[1];
  int c0p = (c0 + 63) & ~63;
  sc[2] = 0;      // cursor branch0
  sc[3] = c0p;    // cursor branch1
  sc[4] = c0;
  sc[5] = c0p;
  sc[6] = c1;
}

__global__ __launch_bounds__(256) void k_partition(const unsigned char* __restrict__ biedge,
    const int* __restrict__ eidx, int* __restrict__ sc,
    int* __restrict__ epos, int* __restrict__ ip, int* __restrict__ jp, int* __restrict__ kp)
{
  int e = blockIdx.x*256 + threadIdx.x;
  bool active = e < E_TRIP;
  int b = active ? (int)biedge[e] : 0;
  unsigned long long m0 = __ballot(active && b==0);
  unsigned long long m1 = __ballot(active && b==1);
  if (active) {
    unsigned long long m = b ? m1 : m0;
    unsigned pre = __builtin_amdgcn_mbcnt_lo((unsigned)m, 0u);
    pre = __builtin_amdgcn_mbcnt_hi((unsigned)(m >> 32), pre);
    int leader = (int)__ffsll((long long)m) - 1;
    int lane = threadIdx.x & 63;
    int base = 0;
    if (lane == leader) base = atomicAdd(&sc[2+b], (int)__popcll(m));
    base = __shfl(base, leader);
    int pos = base + (int)pre;
    epos[pos] = e;
    ip[pos] = eidx[e];
    jp[pos] = eidx[E_TRIP + e];
    kp[pos] = eidx[2*E_TRIP + e];
  }
}

__global__ __launch_bounds__(256) void k_cvt(const float* __restrict__ W0,
    const float* __restrict__ Wr, f16* __restrict__ W0h, f16* __restrict__ Wrh)
{
  int i = blockIdx.x*256 + threadIdx.x;
  if (i < 98304) W0h[i] = (f16)W0[i];
  else { int j = i - 98304; if (j < 73728) Wrh[j] = (f16)Wr[j]; }
}

// ---------------- geo MLP input layer ----------------
__global__ __launch_bounds__(256) void k_geo(
    const float* __restrict__ coords, const float* __restrict__ facex,
    const int* __restrict__ ewf, const int* __restrict__ exij, const int* __restrict__ exjk,
    const float* __restrict__ Wgeo, const float* __restrict__ bgeo,
    const int* __restrict__ sc, const int* __restrict__ epos,
    const int* __restrict__ ip, const int* __restrict__ jp, const int* __restrict__ kp,
    f16* __restrict__ zgeo, float* __restrict__ gstats)
{
  __shared__ f16 lds[256*72];         // 256 rows x 64 feats (+8 pad) f16
  __shared__ float sstat[64][2];
  int tid = threadIdx.x;
  int base = blockIdx.x*256;
  int c0 = sc[4], c0p = sc[5], c1 = sc[6];
  if (tid < 128) ((float*)sstat)[tid] = 0.f;
  // phase A: one thread builds one row's 56 features (f16)
  {
    int p = base + tid;
    bool valid = (p < c0) || (p >= c0p && p < c0p + c1);
    f16* lrow = lds + tid*72;
    if (valid) {
      int e = epos[p];
      int ii = ip[p], jj = jp[p], kk = kp[p];
      float cix = coords[ii*3+0], ciy = coords[ii*3+1], ciz = coords[ii*3+2];
      float cjx = coords[jj*3+0], cjy = coords[jj*3+1], cjz = coords[jj*3+2];
      float ckx = coords[kk*3+0], cky = coords[kk*3+1], ckz = coords[kk*3+2];
      float v1x = cjx-cix, v1y = cjy-ciy, v1z = cjz-ciz;
      float v2x = ckx-cjx, v2y = cky-cjy, v2z = ckz-cjz;
      float dij = sqrtf(v1x*v1x + v1y*v1y + v1z*v1z);
      float djk = sqrtf(v2x*v2x + v2y*v2y + v2z*v2z);
      float cx = v1y*v2z - v1z*v2y;
      float cy = v1z*v2x - v1x*v2z;
      float cz = v1x*v2y - v1y*v2x;
      float theta = atan2f(sqrtf(cx*cx+cy*cy+cz*cz), v1x*v2x+v1y*v2y+v1z*v2z);
      lrow[0]=(f16)dij; lrow[1]=(f16)djk; lrow[2]=(f16)theta; lrow[3]=(f16)0.f;
      lrow[4]=(f16)cjx; lrow[5]=(f16)cjy; lrow[6]=(f16)cjz;
      lrow[7]=(f16)cix; lrow[8]=(f16)ciy; lrow[9]=(f16)ciz;
      int fij = ewf[exij[e]], fjk = ewf[exjk[e]];
      const float* fx1 = facex + (size_t)fij*23;
      const float* fx2 = facex + (size_t)fjk*23;
      for (int c = 0; c < 23; c++) lrow[10+c] = (f16)fx1[c];
      for (int c = 0; c < 23; c++) lrow[33+c] = (f16)fx2[c];
      for (int c = 56; c < 64; c++) lrow[c] = (f16)0.f;
    } else {
      for (int c = 0; c < 64; c++) lrow[c] = (f16)0.f;
    }
  }
  __syncthreads();
  int wv = tid>>6, lane = tid&63, lg = lane>>4, lr = lane&15;
  // B fragments from W_geo [64 out][56 in], k padded to 64 with zeros
  f16x8 Bf[4][2];
  #pragma unroll
  for (int nt = 0; nt < 4; nt++) {
    #pragma unroll
    for (int ks = 0; ks < 2; ks++) {
      int n = nt*16 + lr;
      int kb = ks*32 + lg*8;
      f16x8 w;
      if (kb < 56) {
        float4 w0 = *(const float4*)(Wgeo + n*56 + kb);
        float4 w1 = *(const float4*)(Wgeo + n*56 + kb + 4);
        w[0]=(f16)w0.x; w[1]=(f16)w0.y; w[2]=(f16)w0.z; w[3]=(f16)w0.w;
        w[4]=(f16)w1.x; w[5]=(f16)w1.y; w[6]=(f16)w1.z; w[7]=(f16)w1.w;
      } else {
        #pragma unroll
        for (int j2 = 0; j2 < 8; j2++) w[j2] = (f16)0.f;
      }
      Bf[nt][ks] = w;
    }
  }
  float ssum[4] = {0,0,0,0}, ssq[4] = {0,0,0,0};
  for (int mt = 0; mt < 4; mt++) {
    int rbase = wv*64 + mt*16;
    f16x8 A0 = *(const f16x8*)(lds + (rbase+lr)*72 + lg*8);
    f16x8 A1 = *(const f16x8*)(lds + (rbase+lr)*72 + 32 + lg*8);
    f32x4 acc[4];
    #pragma unroll
    for (int nt = 0; nt < 4; nt++) { acc[nt][0]=0.f; acc[nt][1]=0.f; acc[nt][2]=0.f; acc[nt][3]=0.f; }
    #pragma unroll
    for (int nt = 0; nt < 4; nt++) {
      acc[nt] = __builtin_amdgcn_mfma_f32_16x16x32_f16(A0, Bf[nt][0], acc[nt], 0, 0, 0);
      acc[nt] = __builtin_amdgcn_mfma_f32_16x16x32_f16(A1, Bf[nt][1], acc[nt], 0, 0, 0);
    }
    #pragma unroll
    for (int nt = 0; nt < 4; nt++) {
      int n = nt*16 + lr;
      float bg = bgeo[n];
      #pragma unroll
      for (int rg = 0; rg < 4; rg++) {
        int rloc = rbase + lg*4 + rg;
        int p = base + rloc;
        bool valid = (p < c0) || (p >= c0p && p < c0p + c1);
        float z = valid ? (acc[nt][rg] + bg) : 0.f;
        ssum[nt] += z; ssq[nt] += z*z;
        lds[rloc*72 + n] = (f16)z;
      }
    }
  }
  #pragma unroll
  for (int nt = 0; nt < 4; nt++) {
    float v = ssum[nt]; v += __shfl_xor(v, 16); v += __shfl_xor(v, 32);
    float w = ssq[nt];  w += __shfl_xor(w, 16); w += __shfl_xor(w, 32);
    if (lane < 16) { atomicAdd(&sstat[nt*16+lane][0], v); atomicAdd(&sstat[nt*16+lane][1], w); }
  }
  __syncthreads();
  {
    int p = base + tid;
    #pragma unroll
    for (int c = 0; c < 8; c++) {
      f16x8 v = *(const f16x8*)(lds + tid*72 + c*8);
      *(f16x8*)(zgeo + (size_t)p*64 + c*8) = v;
    }
  }
  if (tid < 128) {
    float v = ((float*)sstat)[tid];
    if (v != 0.f) atomicAdd(&gstats[tid], v);
  }
}

// ---------------- interaction layer 0 (K=256) ----------------
__global__ __launch_bounds__(256) void k_layer0(
    const float* __restrict__ nfprev, const f16* __restrict__ zgeo,
    const f16* __restrict__ W0p, const float* __restrict__ b0p,
    const float* __restrict__ g_geo, const float* __restrict__ be_geo,
    const float* __restrict__ geostats, float* __restrict__ outstats,
    const int* __restrict__ sc, const int* __restrict__ ip,
    const int* __restrict__ jp, const int* __restrict__ kp,
    f16* __restrict__ z0)
{
  __shared__ f16 lds[64*264];   // 64 rows x 256 k (+8 pad)
  __shared__ float geoscale[64], geoshift[64];
  __shared__ float sstat[2][64][2];
  int tid = threadIdx.x;
  int c0 = sc[4], c0p = sc[5], c1 = sc[6];
  if (tid < 64) {
    float s = geostats[tid*2], sq = geostats[tid*2+1];
    float mean = s * (1.f/(float)E_TRIP);
    float var  = sq * (1.f/(float)E_TRIP) - mean*mean;
    float rstd = rsqrtf(var + EPSF);
    float scl = g_geo[tid]*rstd;
    geoscale[tid] = scl;
    geoshift[tid] = be_geo[tid] - mean*scl;
  }
  ((float*)sstat)[tid] = 0.f;
  __syncthreads();
  int wv = tid>>6, lane = tid&63, lg = lane>>4, lr = lane&15;
  float s0sum[4]={0,0,0,0}, s0sq[4]={0,0,0,0}, s1sum[4]={0,0,0,0}, s1sq[4]={0,0,0,0};
  for (int tile = blockIdx.x; tile < NTILE64; tile += gridDim.x) {
    int rowbase = tile*64;
    int branch = (rowbase >= c0p) ? 1 : 0;
    // phase A: stage xcat tile [64 rows][256 k] in f16
    {
      int r = tid >> 2, q = tid & 3;
      int p = rowbase + r;
      bool valid = (p < c0) || (p >= c0p && p < c0p + c1);
      f16* rowp = lds + r*264 + q*64;
      if (q < 3) {
        if (valid) {
          int idx = (q==0 ? ip : (q==1 ? jp : kp))[p];
          const float* src = nfprev + (size_t)idx*64;
          #pragma unroll
          for (int c = 0; c < 8; c++) {
            float4 a  = *(const float4*)(src + c*8);
            float4 b2 = *(const float4*)(src + c*8 + 4);
            f16x8 u;
            u[0]=(f16)a.x; u[1]=(f16)a.y; u[2]=(f16)a.z; u[3]=(f16)a.w;
            u[4]=(f16)b2.x; u[5]=(f16)b2.y; u[6]=(f16)b2.z; u[7]=(f16)b2.w;
            *(f16x8*)(rowp + c*8) = u;
          }
        } else {
          f16x8 u;
          #pragma unroll
          for (int j2 = 0; j2 < 8; j2++) u[j2] = (f16)0.f;
          #pragma unroll
          for (int c = 0; c < 8; c++) *(f16x8*)(rowp + c*8) = u;
        }
      } else {
        if (valid) {
          const f16* zg = zgeo + (size_t)p*64;
          #pragma unroll
          for (int c = 0; c < 8; c++) {
            f16x8 raw = *(const f16x8*)(zg + c*8);
            f16x8 u;
            #pragma unroll
            for (int j2 = 0; j2 < 8; j2++) {
              int f = c*8 + j2;
              float x = fmaxf((float)raw[j2]*geoscale[f] + geoshift[f], 0.f);
              u[j2] = (f16)x;
            }
            *(f16x8*)(rowp + c*8) = u;
          }
        } else {
          f16x8 u;
          #pragma unroll
          for (int j2 = 0; j2 < 8; j2++) u[j2] = (f16)0.f;
          #pragma unroll
          for (int c = 0; c < 8; c++) *(f16x8*)(rowp + c*8) = u;
        }
      }
    }
    __syncthreads();
    // phase B: each wave does 16 rows x 64 cols, K=256
    {
      int r0 = wv*16;
      const f16* Wb = W0p + branch*16384;
      f32x4 acc[4];
      #pragma unroll
      for (int nt = 0; nt < 4; nt++) { acc[nt][0]=0.f; acc[nt][1]=0.f; acc[nt][2]=0.f; acc[nt][3]=0.f; }
      #pragma unroll
      for (int ks = 0; ks < 8; ks++) {
        f16x8 A = *(const f16x8*)(lds + (r0+lr)*264 + (ks*4+lg)*8);
        #pragma unroll
        for (int nt = 0; nt < 4; nt++) {
          f16x8 B = *(const f16x8*)(Wb + (nt*16+lr)*256 + ks*32 + lg*8);
          acc[nt] = __builtin_amdgcn_mfma_f32_16x16x32_f16(A, B, acc[nt], 0, 0, 0);
        }
      }
      #pragma unroll
      for (int nt = 0; nt < 4; nt++) {
        int n = nt*16 + lr;
        float bias = b0p[branch*64 + n];
        #pragma unroll
        for (int rg = 0; rg < 4; rg++) {
          int rloc = r0 + lg*4 + rg;
          int p = rowbase + rloc;
          bool valid = (p < c0) || (p >= c0p && p < c0p + c1);
          float z = valid ? (acc[nt][rg] + bias) : 0.f;
          if (branch == 0) { s0sum[nt] += z; s0sq[nt] += z*z; }
          else             { s1sum[nt] += z; s1sq[nt] += z*z; }
          lds[rloc*264 + n] = (f16)z;
        }
      }
    }
    __syncthreads();
    // store
    {
      int r = tid>>2, q = tid&3;
      int p = rowbase + r;
      f16x8 v0 = *(const f16x8*)(lds + r*264 + q*16);
      f16x8 v1 = *(const f16x8*)(lds + r*264 + q*16 + 8);
      *(f16x8*)(z0 + (size_t)p*64 + q*16) = v0;
      *(f16x8*)(z0 + (size_t)p*64 + q*16 + 8) = v1;
    }
    __syncthreads();
  }
  #pragma unroll
  for (int nt = 0; nt < 4; nt++) {
    float v, w;
    v = s0sum[nt]; v += __shfl_xor(v,16); v += __shfl_xor(v,32);
    w = s0sq[nt];  w += __shfl_xor(w,16); w += __shfl_xor(w,32);
    if (lane < 16) { atomicAdd(&sstat[0][nt*16+lane][0], v); atomicAdd(&sstat[0][nt*16+lane][1], w); }
    v = s1sum[nt]; v += __shfl_xor(v,16); v += __shfl_xor(v,32);
    w = s1sq[nt];  w += __shfl_xor(w,16); w += __shfl_xor(w,32);
    if (lane < 16) { atomicAdd(&sstat[1][nt*16+lane][0], v); atomicAdd(&sstat[1][nt*16+lane][1], w); }
  }
  __syncthreads();
  {
    float v = ((float*)sstat)[tid];
    if (v != 0.f) atomicAdd(&outstats[tid], v);
  }
}

// ---------------- hidden layers (K=64) ----------------
__global__ __launch_bounds__(256) void k_hidden(
    const f16* __restrict__ zin, f16* __restrict__ zout,
    const f16* __restrict__ Wp, const float* __restrict__ biasp,
    const float* __restrict__ bngp, const float* __restrict__ bnbp,
    const float* __restrict__ instats, float* __restrict__ outstats,
    const int* __restrict__ sc)
{
  __shared__ f16 ldso[64*72];
  __shared__ float lscale[2][64], lshift[2][64];
  __shared__ float sstat[2][64][2];
  int tid = threadIdx.x;
  int c0 = sc[4], c0p = sc[5], c1 = sc[6];
  if (tid < 128) {
    int b = tid>>6, n = tid&63;
    int cb = b ? c1 : c0; if (cb < 1) cb = 1;
    float inv = 1.f/(float)cb;
    float s = instats[(b*64+n)*2], sq = instats[(b*64+n)*2+1];
    float mean = s*inv, var = sq*inv - mean*mean;
    float rstd = rsqrtf(var + EPSF);
    float scl = bngp[b*256+n]*rstd;
    lscale[b][n] = scl;
    lshift[b][n] = bnbp[b*256+n] - mean*scl;
  }
  ((float*)sstat)[tid] = 0.f;
  __syncthreads();
  int wv = tid>>6, lane = tid&63, lg = lane>>4, lr = lane&15;
  float s0sum[4]={0,0,0,0}, s0sq[4]={0,0,0,0}, s1sum[4]={0,0,0,0}, s1sq[4]={0,0,0,0};
  for (int tile = blockIdx.x; tile < NTILE64; tile += gridDim.x) {
    int rowbase = tile*64;
    int branch = (rowbase >= c0p) ? 1 : 0;
    int rgl = rowbase + wv*16 + lr;
    f16x8 Af[2];
    #pragma unroll
    for (int ks = 0; ks < 2; ks++) {
      f16x8 raw = *(const f16x8*)(zin + (size_t)rgl*64 + ks*32 + lg*8);
      f16x8 A;
      #pragma unroll
      for (int j2 = 0; j2 < 8; j2++) {
        int f = ks*32 + lg*8 + j2;
        float x = fmaxf((float)raw[j2]*lscale[branch][f] + lshift[branch][f], 0.f);
        A[j2] = (f16)x;
      }
      Af[ks] = A;
    }
    f32x4 acc[4];
    #pragma unroll
    for (int nt = 0; nt < 4; nt++) { acc[nt][0]=0.f; acc[nt][1]=0.f; acc[nt][2]=0.f; acc[nt][3]=0.f; }
    #pragma unroll
    for (int ks = 0; ks < 2; ks++) {
      #pragma unroll
      for (int nt = 0; nt < 4; nt++) {
        f16x8 B = *(const f16x8*)(Wp + branch*12288 + (nt*16+lr)*64 + ks*32 + lg*8);
        acc[nt] = __builtin_amdgcn_mfma_f32_16x16x32_f16(Af[ks], B, acc[nt], 0, 0, 0);
      }
    }
    #pragma unroll
    for (int nt = 0; nt < 4; nt++) {
      int n = nt*16 + lr;
      float bias = biasp[branch*192 + n];
      #pragma unroll
      for (int rg = 0; rg < 4; rg++) {
        int rloc = wv*16 + lg*4 + rg;
        int p = rowbase + rloc;
        bool valid = (p < c0) || (p >= c0p && p < c0p + c1);
        float z = valid ? (acc[nt][rg] + bias) : 0.f;
        if (branch == 0) { s0sum[nt] += z; s0sq[nt] += z*z; }
        else             { s1sum[nt] += z; s1sq[nt] += z*z; }
        ldso[rloc*72 + n] = (f16)z;
      }
    }
    __syncthreads();
    {
      int r = tid>>2, q = tid&3;
      int p = rowbase + r;
      f16x8 v0 = *(const f16x8*)(ldso + r*72 + q*16);
      f16x8 v1 = *(const f16x8*)(ldso + r*72 + q*16 + 8);
      *(f16x8*)(zout + (size_t)p*64 + q*16) = v0;
      *(f16x8*)(zout + (size_t)p*64 + q*16 + 8) = v1;
    }
    __syncthreads();
  }
  #pragma unroll
  for (int nt = 0; nt < 4; nt++) {
    float v, w;
    v = s0sum[nt]; v += __shfl_xor(v,16); v += __shfl_xor(v,32);
    w = s0sq[nt];  w += __shfl_xor(w,16); w += __shfl_xor(w,32);
    if (lane < 16) { atomicAdd(&sstat[0][nt*16+lane][0], v); atomicAdd(&sstat[0][nt*16+lane][1], w); }
    v = s1sum[nt]; v += __shfl_xor(v,16); v += __shfl_xor(v,32);
    w = s1sq[nt];  w += __shfl_xor(w,16); w += __shfl_xor(w,32);
    if (lane < 16) { atomicAdd(&sstat[1][nt*16+lane][0], v); atomicAdd(&sstat[1][nt*16+lane][1], w); }
  }
  __syncthreads();
  {
    float v = ((float*)sstat)[tid];
    if (v != 0.f) atomicAdd(&outstats[tid], v);
  }
}

// ---------------- final BN + relu + att + scatter-add ----------------
__global__ __launch_bounds__(256) void k_final(
    const f16* __restrict__ z3, const float* __restrict__ att,
    const float* __restrict__ bngp, const float* __restrict__ bnbp,
    const float* __restrict__ instats, const int* __restrict__ sc,
    const int* __restrict__ ip, float* __restrict__ outt)
{
  __shared__ float lscale[2][64], lshift[2][64];
  int tid = threadIdx.x;
  int c0 = sc[4], c0p = sc[5], c1 = sc[6];
  if (tid < 128) {
    int b = tid>>6, n = tid&63;
    int cb = b ? c1 : c0; if (cb < 1) cb = 1;
    float inv = 1.f/(float)cb;
    float s = instats[(b*64+n)*2], sq = instats[(b*64+n)*2+1];
    float mean = s*inv, var = sq*inv - mean*mean;
    float rstd = rsqrtf(var + EPSF);
    float scl = bngp[b*256+n]*rstd;
    lscale[b][n] = scl;
    lshift[b][n] = bnbp[b*256+n] - mean*scl;
  }
  __syncthreads();
  long long gid = (long long)blockIdx.x*256 + tid;
  int p = (int)(gid >> 3), q = (int)(gid & 7);
  if (p >= EPAD) return;
  bool valid = (p < c0) || (p >= c0p && p < c0p + c1);
  if (!valid) return;
  int b = (p >= c0p) ? 1 : 0;
  float a = att[b];
  f16x8 raw = *(const f16x8*)(z3 + (size_t)p*64 + q*8);
  float* dst = outt + (size_t)ip[p]*64 + q*8;
  #pragma unroll
  for (int j2 = 0; j2 < 8; j2++) {
    int f = q*8 + j2;
    float x = fmaxf((float)raw[j2]*lscale[b][f] + lshift[b][f], 0.f);
    atomicAdd(&dst[j2], x*a);   // leaky_relu is identity for x>=0
  }
}

extern "C" void kernel_launch(void* const* d_in, const int* in_sizes, int n_in,
                              void* d_out, int out_size, void* d_ws, size_t ws_size,
                              hipStream_t stream)
{
  const float* input_feature = (const float*)d_in[0];
  const float* coords   = (const float*)d_in[1];
  const float* face_x   = (const float*)d_in[3];
  const float* att      = (const float*)d_in[4];
  const float* W_geo    = (const float*)d_in[5];
  const float* b_geo    = (const float*)d_in[6];
  const float* g_geo    = (const float*)d_in[7];
  const float* be_geo   = (const float*)d_in[8];
  const float* spnn_W0  = (const float*)d_in[9];
  const float* spnn_b0  = (const float*)d_in[10];
  const float* spnn_Wr  = (const float*)d_in[11];
  const float* spnn_br  = (const float*)d_in[12];
  const float* bn_g     = (const float*)d_in[13];
  const float* bn_b     = (const float*)d_in[14];
  const int* ewf  = (const int*)d_in[15];
  const int* eidx = (const int*)d_in[16];
  const int* exjk = (const int*)d_in[17];
  const int* exij = (const int*)d_in[18];
  float* out = (float*)d_out;
  char* ws = (char*)d_ws;

  size_t off = 0;
  auto take = [&](size_t bytes) -> char* {
    size_t o = off; off = (off + bytes + 255) & ~(size_t)255; return ws + o;
  };
  int*   sc     = (int*)take(256);
  float* stats  = (float*)take(13*256*sizeof(float));  // geo + 3*4 layer stat buffers, each [2][64][2]
  unsigned char* biedge = (unsigned char*)take(E_TRIP);
  int* epos = (int*)take(sizeof(int)*EPAD);
  int* ip   = (int*)take(sizeof(int)*EPAD);
  int* jp   = (int*)take(sizeof(int)*EPAD);
  int* kp   = (int*)take(sizeof(int)*EPAD);
  f16* W0h  = (f16*)take(sizeof(f16)*3*2*64*256);
  f16* Wrh  = (f16*)take(sizeof(f16)*3*2*3*64*64);
  f16* zgeo = (f16*)take(sizeof(f16)*(size_t)EPAD*64);
  f16* zA   = (f16*)take(sizeof(f16)*(size_t)EPAD*64);
  f16* zB   = (f16*)take(sizeof(f16)*(size_t)EPAD*64);
  if (off > ws_size) return;  // workspace insufficient; cannot run

  hipMemsetAsync(sc, 0, 256 + 13*256*sizeof(float), stream);
  hipMemsetAsync(out, 0, sizeof(float)*(size_t)out_size, stream);

  k_count    <<<1954, 256, 0, stream>>>(ewf, exij, exjk, biedge, sc);
  k_scal     <<<1, 1, 0, stream>>>(sc);
  k_partition<<<1954, 256, 0, stream>>>(biedge, eidx, sc, epos, ip, jp, kp);
  k_cvt      <<<672, 256, 0, stream>>>(spnn_W0, spnn_Wr, W0h, Wrh);
  k_geo      <<<NBLK256, 256, 0, stream>>>(coords, face_x, ewf, exij, exjk, W_geo, b_geo,
                                           sc, epos, ip, jp, kp, zgeo, stats);
  for (int t = 0; t < 3; t++) {
    const float* nfprev = (t == 0) ? input_feature : (out + (size_t)(t-1)*NN*64);
    float* outt = out + (size_t)t*NN*64;
    k_layer0<<<1024, 256, 0, stream>>>(nfprev, zgeo,
        W0h + (size_t)t*2*64*256, spnn_b0 + t*2*64,
        g_geo, be_geo, stats, stats + (size_t)(1 + t*4)*256,
        sc, ip, jp, kp, zA);
    f16* zi = zA; f16* zo = zB;
    for (int h = 0; h < 3; h++) {
      k_hidden<<<1024, 256, 0, stream>>>(zi, zo,
          Wrh + (size_t)t*2*3*64*64 + (size_t)h*64*64,
          spnn_br + t*2*3*64 + h*64,
          bn_g + t*2*4*64 + h*64,
          bn_b + t*2*4*64 + h*64,
          stats + (size_t)(1 + t*4 + h)*256,
          stats + (size_t)(1 + t*4 + h + 1)*256,
          sc);
      f16* tmp = zi; zi = zo; zo = tmp;
    }
    k_final<<<EPAD*8/256, 256, 0, stream>>>(zi, att,
        bn_g + t*2*4*64 + 3*64, bn_b + t*2*4*64 + 3*64,
        stats + (size_t)(1 + t*4 + 3)*256, sc, ip, outt);
  }
}

// Round 2
// 1796.775 us; speedup vs baseline: 2.4473x; 2.4473x over previous
//
#include <hip/hip_runtime.h>

#define E_TRIP 500000
#define EPAD   500224              // multiple of 256; >= c0_pad + c1 always
#define NTILE64 (EPAD/64)          // 7816
#define NBLK256 (EPAD/256)         // 1954
#define NN 100000
#define EPSF 1e-5f

typedef _Float16 f16;
typedef _Float16 f16x8 __attribute__((ext_vector_type(8)));
typedef float f32x4 __attribute__((ext_vector_type(4)));

// ---------------- prep ----------------
__global__ __launch_bounds__(256) void k_count(const int* __restrict__ ewf,
    const int* __restrict__ exij, const int* __restrict__ exjk,
    unsigned char* __restrict__ biedge, int* __restrict__ sc)
{
  int e = blockIdx.x*256 + threadIdx.x;
  bool active = e < E_TRIP;
  int b = 0;
  if (active) {
    int fij = ewf[exij[e]];
    int fjk = ewf[exjk[e]];
    b = (fij == fjk) ? 0 : 1;
    biedge[e] = (unsigned char)b;
  }
  unsigned long long m0 = __ballot(active && b==0);
  unsigned long long m1 = __ballot(active && b==1);
  int lane = threadIdx.x & 63;
  if (m0 && lane == (__ffsll((long long)m0)-1)) atomicAdd(&sc[0], (int)__popcll(m0));
  if (m1 && lane == (__ffsll((long long)m1)-1)) atomicAdd(&sc[1], (int)__popcll(m1));
}

__global__ void k_scal(int* sc)
{
  int c0 = sc[0], c1 = sc[1];
  int c0p = (c0 + 63) & ~63;
  sc[2] = 0;      // cursor branch0
  sc[3] = c0p;    // cursor branch1
  sc[4] = c0;
  sc[5] = c0p;
  sc[6] = c1;
}

__global__ __launch_bounds__(256) void k_partition(const unsigned char* __restrict__ biedge,
    const int* __restrict__ eidx, int* __restrict__ sc,
    int* __restrict__ epos, int* __restrict__ ip, int* __restrict__ jp, int* __restrict__ kp)
{
  int e = blockIdx.x*256 + threadIdx.x;
  bool active = e < E_TRIP;
  int b = active ? (int)biedge[e] : 0;
  unsigned long long m0 = __ballot(active && b==0);
  unsigned long long m1 = __ballot(active && b==1);
  if (active) {
    unsigned long long m = b ? m1 : m0;
    unsigned pre = __builtin_amdgcn_mbcnt_lo((unsigned)m, 0u);
    pre = __builtin_amdgcn_mbcnt_hi((unsigned)(m >> 32), pre);
    int leader = (int)__ffsll((long long)m) - 1;
    int lane = threadIdx.x & 63;
    int base = 0;
    if (lane == leader) base = atomicAdd(&sc[2+b], (int)__popcll(m));
    base = __shfl(base, leader);
    int pos = base + (int)pre;
    epos[pos] = e;
    ip[pos] = eidx[e];
    jp[pos] = eidx[E_TRIP + e];
    kp[pos] = eidx[2*E_TRIP + e];
  }
}

__global__ __launch_bounds__(256) void k_cvt(const float* __restrict__ W0,
    const float* __restrict__ Wr, const float* __restrict__ nf,
    f16* __restrict__ W0h, f16* __restrict__ Wrh, f16* __restrict__ nfh)
{
  int i = blockIdx.x*256 + threadIdx.x;
  if (i < 98304) W0h[i] = (f16)W0[i];
  else if (i < 98304 + 73728) Wrh[i - 98304] = (f16)Wr[i - 98304];
  else { int j = i - 172032; if (j < NN*64) nfh[j] = (f16)nf[j]; }
}

// ---- destination counting sort (runs once; i is interaction-invariant) ----
__global__ __launch_bounds__(256) void k_hist(const int* __restrict__ ip,
    const int* __restrict__ sc, int* __restrict__ cnt)
{
  int p = blockIdx.x*256 + threadIdx.x;
  int c0 = sc[4], c0p = sc[5], c1 = sc[6];
  bool valid = (p < c0) || (p >= c0p && p < c0p + c1);
  if (valid) atomicAdd(&cnt[ip[p]], 1);
}

__global__ __launch_bounds__(512) void k_scan1(const int* __restrict__ cnt,
    int* __restrict__ start, int* __restrict__ btot)
{
  __shared__ int s[512];
  int tid = threadIdx.x;
  int g = blockIdx.x*512 + tid;
  int x = (g < NN) ? cnt[g] : 0;
  s[tid] = x; __syncthreads();
  #pragma unroll
  for (int off = 1; off < 512; off <<= 1) {
    int v = (tid >= off) ? s[tid-off] : 0;
    __syncthreads();
    s[tid] += v;
    __syncthreads();
  }
  if (g < NN) start[g] = s[tid] - x;   // exclusive within chunk
  if (tid == 511) btot[blockIdx.x] = s[511];
}

__global__ __launch_bounds__(256) void k_scan2(int* __restrict__ btot)
{
  __shared__ int s[256];
  int tid = threadIdx.x;
  int x = (tid < 196) ? btot[tid] : 0;
  s[tid] = x; __syncthreads();
  #pragma unroll
  for (int off = 1; off < 256; off <<= 1) {
    int v = (tid >= off) ? s[tid-off] : 0;
    __syncthreads();
    s[tid] += v;
    __syncthreads();
  }
  if (tid < 196) btot[tid] = s[tid] - x;  // exclusive
}

__global__ __launch_bounds__(512) void k_scan3(int* __restrict__ start,
    int* __restrict__ cur, const int* __restrict__ btot, const int* __restrict__ sc)
{
  int tid = threadIdx.x;
  int g = blockIdx.x*512 + tid;
  if (g < NN) {
    int v = start[g] + btot[blockIdx.x];
    start[g] = v;
    cur[g] = v;
  }
  if (g == 0) start[NN] = sc[4] + sc[6];
}

__global__ __launch_bounds__(256) void k_place(const int* __restrict__ ip,
    const int* __restrict__ sc, int* __restrict__ cur, int* __restrict__ dperm)
{
  int p = blockIdx.x*256 + threadIdx.x;
  int c0 = sc[4], c0p = sc[5], c1 = sc[6];
  bool valid = (p < c0) || (p >= c0p && p < c0p + c1);
  if (valid) {
    int pos = atomicAdd(&cur[ip[p]], 1);
    dperm[pos] = p;
  }
}

// ---------------- geo MLP input layer ----------------
__global__ __launch_bounds__(256) void k_geo(
    const float* __restrict__ coords, const float* __restrict__ facex,
    const int* __restrict__ ewf, const int* __restrict__ exij, const int* __restrict__ exjk,
    const float* __restrict__ Wgeo, const float* __restrict__ bgeo,
    const int* __restrict__ sc, const int* __restrict__ epos,
    const int* __restrict__ ip, const int* __restrict__ jp, const int* __restrict__ kp,
    f16* __restrict__ zgeo, float* __restrict__ gstats)
{
  __shared__ f16 lds[256*72];         // 256 rows x 64 feats (+8 pad) f16
  __shared__ float sstat[64][2];
  int tid = threadIdx.x;
  int base = blockIdx.x*256;
  int c0 = sc[4], c0p = sc[5], c1 = sc[6];
  if (tid < 128) ((float*)sstat)[tid] = 0.f;
  // phase A: one thread builds one row's 56 features (f16)
  {
    int p = base + tid;
    bool valid = (p < c0) || (p >= c0p && p < c0p + c1);
    f16* lrow = lds + tid*72;
    if (valid) {
      int e = epos[p];
      int ii = ip[p], jj = jp[p], kk = kp[p];
      float cix = coords[ii*3+0], ciy = coords[ii*3+1], ciz = coords[ii*3+2];
      float cjx = coords[jj*3+0], cjy = coords[jj*3+1], cjz = coords[jj*3+2];
      float ckx = coords[kk*3+0], cky = coords[kk*3+1], ckz = coords[kk*3+2];
      float v1x = cjx-cix, v1y = cjy-ciy, v1z = cjz-ciz;
      float v2x = ckx-cjx, v2y = cky-cjy, v2z = ckz-cjz;
      float dij = sqrtf(v1x*v1x + v1y*v1y + v1z*v1z);
      float djk = sqrtf(v2x*v2x + v2y*v2y + v2z*v2z);
      float cx = v1y*v2z - v1z*v2y;
      float cy = v1z*v2x - v1x*v2z;
      float cz = v1x*v2y - v1y*v2x;
      float theta = atan2f(sqrtf(cx*cx+cy*cy+cz*cz), v1x*v2x+v1y*v2y+v1z*v2z);
      lrow[0]=(f16)dij; lrow[1]=(f16)djk; lrow[2]=(f16)theta; lrow[3]=(f16)0.f;
      lrow[4]=(f16)cjx; lrow[5]=(f16)cjy; lrow[6]=(f16)cjz;
      lrow[7]=(f16)cix; lrow[8]=(f16)ciy; lrow[9]=(f16)ciz;
      int fij = ewf[exij[e]], fjk = ewf[exjk[e]];
      const float* fx1 = facex + (size_t)fij*23;
      const float* fx2 = facex + (size_t)fjk*23;
      for (int c = 0; c < 23; c++) lrow[10+c] = (f16)fx1[c];
      for (int c = 0; c < 23; c++) lrow[33+c] = (f16)fx2[c];
      for (int c = 56; c < 64; c++) lrow[c] = (f16)0.f;
    } else {
      for (int c = 0; c < 64; c++) lrow[c] = (f16)0.f;
    }
  }
  __syncthreads();
  int wv = tid>>6, lane = tid&63, lg = lane>>4, lr = lane&15;
  // B fragments from W_geo [64 out][56 in], k padded to 64 with zeros
  f16x8 Bf[4][2];
  #pragma unroll
  for (int nt = 0; nt < 4; nt++) {
    #pragma unroll
    for (int ks = 0; ks < 2; ks++) {
      int n = nt*16 + lr;
      int kb = ks*32 + lg*8;
      f16x8 w;
      if (kb < 56) {
        float4 w0 = *(const float4*)(Wgeo + n*56 + kb);
        float4 w1 = *(const float4*)(Wgeo + n*56 + kb + 4);
        w[0]=(f16)w0.x; w[1]=(f16)w0.y; w[2]=(f16)w0.z; w[3]=(f16)w0.w;
        w[4]=(f16)w1.x; w[5]=(f16)w1.y; w[6]=(f16)w1.z; w[7]=(f16)w1.w;
      } else {
        #pragma unroll
        for (int j2 = 0; j2 < 8; j2++) w[j2] = (f16)0.f;
      }
      Bf[nt][ks] = w;
    }
  }
  float ssum[4] = {0,0,0,0}, ssq[4] = {0,0,0,0};
  for (int mt = 0; mt < 4; mt++) {
    int rbase = wv*64 + mt*16;
    f16x8 A0 = *(const f16x8*)(lds + (rbase+lr)*72 + lg*8);
    f16x8 A1 = *(const f16x8*)(lds + (rbase+lr)*72 + 32 + lg*8);
    f32x4 acc[4];
    #pragma unroll
    for (int nt = 0; nt < 4; nt++) { acc[nt][0]=0.f; acc[nt][1]=0.f; acc[nt][2]=0.f; acc[nt][3]=0.f; }
    #pragma unroll
    for (int nt = 0; nt < 4; nt++) {
      acc[nt] = __builtin_amdgcn_mfma_f32_16x16x32_f16(A0, Bf[nt][0], acc[nt], 0, 0, 0);
      acc[nt] = __builtin_amdgcn_mfma_f32_16x16x32_f16(A1, Bf[nt][1], acc[nt], 0, 0, 0);
    }
    #pragma unroll
    for (int nt = 0; nt < 4; nt++) {
      int n = nt*16 + lr;
      float bg = bgeo[n];
      #pragma unroll
      for (int rg = 0; rg < 4; rg++) {
        int rloc = rbase + lg*4 + rg;
        int p = base + rloc;
        bool valid = (p < c0) || (p >= c0p && p < c0p + c1);
        float z = valid ? (acc[nt][rg] + bg) : 0.f;
        ssum[nt] += z; ssq[nt] += z*z;
        lds[rloc*72 + n] = (f16)z;
      }
    }
  }
  #pragma unroll
  for (int nt = 0; nt < 4; nt++) {
    float v = ssum[nt]; v += __shfl_xor(v, 16); v += __shfl_xor(v, 32);
    float w = ssq[nt];  w += __shfl_xor(w, 16); w += __shfl_xor(w, 32);
    if (lane < 16) { atomicAdd(&sstat[nt*16+lane][0], v); atomicAdd(&sstat[nt*16+lane][1], w); }
  }
  __syncthreads();
  {
    int p = base + tid;
    #pragma unroll
    for (int c = 0; c < 8; c++) {
      f16x8 v = *(const f16x8*)(lds + tid*72 + c*8);
      *(f16x8*)(zgeo + (size_t)p*64 + c*8) = v;
    }
  }
  if (tid < 128) {
    float v = ((float*)sstat)[tid];
    if (v != 0.f) atomicAdd(&gstats[tid], v);
  }
}

// ---------------- interaction layer 0 (K=256) ----------------
__global__ __launch_bounds__(256) void k_layer0(
    const f16* __restrict__ nfsrc, const f16* __restrict__ zgeo,
    const f16* __restrict__ W0p, const float* __restrict__ b0p,
    const float* __restrict__ g_geo, const float* __restrict__ be_geo,
    const float* __restrict__ geostats, float* __restrict__ outstats,
    const int* __restrict__ sc, const int* __restrict__ ip,
    const int* __restrict__ jp, const int* __restrict__ kp,
    f16* __restrict__ z0)
{
  __shared__ f16 lds[64*264];   // 64 rows x 256 k (+8 pad)
  __shared__ float geoscale[64], geoshift[64];
  __shared__ float sstat[2][64][2];
  int tid = threadIdx.x;
  int c0 = sc[4], c0p = sc[5], c1 = sc[6];
  if (tid < 64) {
    float s = geostats[tid*2], sq = geostats[tid*2+1];
    float mean = s * (1.f/(float)E_TRIP);
    float var  = sq * (1.f/(float)E_TRIP) - mean*mean;
    float rstd = rsqrtf(var + EPSF);
    float scl = g_geo[tid]*rstd;
    geoscale[tid] = scl;
    geoshift[tid] = be_geo[tid] - mean*scl;
  }
  ((float*)sstat)[tid] = 0.f;
  __syncthreads();
  int wv = tid>>6, lane = tid&63, lg = lane>>4, lr = lane&15;
  float s0sum[4]={0,0,0,0}, s0sq[4]={0,0,0,0}, s1sum[4]={0,0,0,0}, s1sq[4]={0,0,0,0};
  for (int tile = blockIdx.x; tile < NTILE64; tile += gridDim.x) {
    int rowbase = tile*64;
    int branch = (rowbase >= c0p) ? 1 : 0;
    // phase A: stage xcat tile [64 rows][256 k] in f16
    {
      int r = tid >> 2, q = tid & 3;
      int p = rowbase + r;
      bool valid = (p < c0) || (p >= c0p && p < c0p + c1);
      f16* rowp = lds + r*264 + q*64;
      if (q < 3) {
        if (valid) {
          int idx = (q==0 ? ip : (q==1 ? jp : kp))[p];
          const f16* src = nfsrc + (size_t)idx*64;
          #pragma unroll
          for (int c = 0; c < 8; c++) *(f16x8*)(rowp + c*8) = *(const f16x8*)(src + c*8);
        } else {
          f16x8 u;
          #pragma unroll
          for (int j2 = 0; j2 < 8; j2++) u[j2] = (f16)0.f;
          #pragma unroll
          for (int c = 0; c < 8; c++) *(f16x8*)(rowp + c*8) = u;
        }
      } else {
        if (valid) {
          const f16* zg = zgeo + (size_t)p*64;
          #pragma unroll
          for (int c = 0; c < 8; c++) {
            f16x8 raw = *(const f16x8*)(zg + c*8);
            f16x8 u;
            #pragma unroll
            for (int j2 = 0; j2 < 8; j2++) {
              int f = c*8 + j2;
              float x = fmaxf((float)raw[j2]*geoscale[f] + geoshift[f], 0.f);
              u[j2] = (f16)x;
            }
            *(f16x8*)(rowp + c*8) = u;
          }
        } else {
          f16x8 u;
          #pragma unroll
          for (int j2 = 0; j2 < 8; j2++) u[j2] = (f16)0.f;
          #pragma unroll
          for (int c = 0; c < 8; c++) *(f16x8*)(rowp + c*8) = u;
        }
      }
    }
    __syncthreads();
    // phase B: each wave does 16 rows x 64 cols, K=256
    {
      int r0 = wv*16;
      const f16* Wb = W0p + branch*16384;
      f32x4 acc[4];
      #pragma unroll
      for (int nt = 0; nt < 4; nt++) { acc[nt][0]=0.f; acc[nt][1]=0.f; acc[nt][2]=0.f; acc[nt][3]=0.f; }
      #pragma unroll
      for (int ks = 0; ks < 8; ks++) {
        f16x8 A = *(const f16x8*)(lds + (r0+lr)*264 + (ks*4+lg)*8);
        #pragma unroll
        for (int nt = 0; nt < 4; nt++) {
          f16x8 B = *(const f16x8*)(Wb + (nt*16+lr)*256 + ks*32 + lg*8);
          acc[nt] = __builtin_amdgcn_mfma_f32_16x16x32_f16(A, B, acc[nt], 0, 0, 0);
        }
      }
      #pragma unroll
      for (int nt = 0; nt < 4; nt++) {
        int n = nt*16 + lr;
        float bias = b0p[branch*64 + n];
        #pragma unroll
        for (int rg = 0; rg < 4; rg++) {
          int rloc = r0 + lg*4 + rg;
          int p = rowbase + rloc;
          bool valid = (p < c0) || (p >= c0p && p < c0p + c1);
          float z = valid ? (acc[nt][rg] + bias) : 0.f;
          if (branch == 0) { s0sum[nt] += z; s0sq[nt] += z*z; }
          else             { s1sum[nt] += z; s1sq[nt] += z*z; }
          lds[rloc*264 + n] = (f16)z;
        }
      }
    }
    __syncthreads();
    // store
    {
      int r = tid>>2, q = tid&3;
      int p = rowbase + r;
      f16x8 v0 = *(const f16x8*)(lds + r*264 + q*16);
      f16x8 v1 = *(const f16x8*)(lds + r*264 + q*16 + 8);
      *(f16x8*)(z0 + (size_t)p*64 + q*16) = v0;
      *(f16x8*)(z0 + (size_t)p*64 + q*16 + 8) = v1;
    }
    __syncthreads();
  }
  #pragma unroll
  for (int nt = 0; nt < 4; nt++) {
    float v, w;
    v = s0sum[nt]; v += __shfl_xor(v,16); v += __shfl_xor(v,32);
    w = s0sq[nt];  w += __shfl_xor(w,16); w += __shfl_xor(w,32);
    if (lane < 16) { atomicAdd(&sstat[0][nt*16+lane][0], v); atomicAdd(&sstat[0][nt*16+lane][1], w); }
    v = s1sum[nt]; v += __shfl_xor(v,16); v += __shfl_xor(v,32);
    w = s1sq[nt];  w += __shfl_xor(w,16); w += __shfl_xor(w,32);
    if (lane < 16) { atomicAdd(&sstat[1][nt*16+lane][0], v); atomicAdd(&sstat[1][nt*16+lane][1], w); }
  }
  __syncthreads();
  {
    float v = ((float*)sstat)[tid];
    if (v != 0.f) atomicAdd(&outstats[tid], v);
  }
}

// ---------------- hidden layers (K=64) ----------------
__global__ __launch_bounds__(256) void k_hidden(
    const f16* __restrict__ zin, f16* __restrict__ zout,
    const f16* __restrict__ Wp, const float* __restrict__ biasp,
    const float* __restrict__ bngp, const float* __restrict__ bnbp,
    const float* __restrict__ instats, float* __restrict__ outstats,
    const int* __restrict__ sc)
{
  __shared__ f16 ldso[64*72];
  __shared__ float lscale[2][64], lshift[2][64];
  __shared__ float sstat[2][64][2];
  int tid = threadIdx.x;
  int c0 = sc[4], c0p = sc[5], c1 = sc[6];
  if (tid < 128) {
    int b = tid>>6, n = tid&63;
    int cb = b ? c1 : c0; if (cb < 1) cb = 1;
    float inv = 1.f/(float)cb;
    float s = instats[(b*64+n)*2], sq = instats[(b*64+n)*2+1];
    float mean = s*inv, var = sq*inv - mean*mean;
    float rstd = rsqrtf(var + EPSF);
    float scl = bngp[b*256+n]*rstd;
    lscale[b][n] = scl;
    lshift[b][n] = bnbp[b*256+n] - mean*scl;
  }
  ((float*)sstat)[tid] = 0.f;
  __syncthreads();
  int wv = tid>>6, lane = tid&63, lg = lane>>4, lr = lane&15;
  float s0sum[4]={0,0,0,0}, s0sq[4]={0,0,0,0}, s1sum[4]={0,0,0,0}, s1sq[4]={0,0,0,0};
  for (int tile = blockIdx.x; tile < NTILE64; tile += gridDim.x) {
    int rowbase = tile*64;
    int branch = (rowbase >= c0p) ? 1 : 0;
    int rgl = rowbase + wv*16 + lr;
    f16x8 Af[2];
    #pragma unroll
    for (int ks = 0; ks < 2; ks++) {
      f16x8 raw = *(const f16x8*)(zin + (size_t)rgl*64 + ks*32 + lg*8);
      f16x8 A;
      #pragma unroll
      for (int j2 = 0; j2 < 8; j2++) {
        int f = ks*32 + lg*8 + j2;
        float x = fmaxf((float)raw[j2]*lscale[branch][f] + lshift[branch][f], 0.f);
        A[j2] = (f16)x;
      }
      Af[ks] = A;
    }
    f32x4 acc[4];
    #pragma unroll
    for (int nt = 0; nt < 4; nt++) { acc[nt][0]=0.f; acc[nt][1]=0.f; acc[nt][2]=0.f; acc[nt][3]=0.f; }
    #pragma unroll
    for (int ks = 0; ks < 2; ks++) {
      #pragma unroll
      for (int nt = 0; nt < 4; nt++) {
        f16x8 B = *(const f16x8*)(Wp + branch*12288 + (nt*16+lr)*64 + ks*32 + lg*8);
        acc[nt] = __builtin_amdgcn_mfma_f32_16x16x32_f16(Af[ks], B, acc[nt], 0, 0, 0);
      }
    }
    #pragma unroll
    for (int nt = 0; nt < 4; nt++) {
      int n = nt*16 + lr;
      float bias = biasp[branch*192 + n];
      #pragma unroll
      for (int rg = 0; rg < 4; rg++) {
        int rloc = wv*16 + lg*4 + rg;
        int p = rowbase + rloc;
        bool valid = (p < c0) || (p >= c0p && p < c0p + c1);
        float z = valid ? (acc[nt][rg] + bias) : 0.f;
        if (branch == 0) { s0sum[nt] += z; s0sq[nt] += z*z; }
        else             { s1sum[nt] += z; s1sq[nt] += z*z; }
        ldso[rloc*72 + n] = (f16)z;
      }
    }
    __syncthreads();
    {
      int r = tid>>2, q = tid&3;
      int p = rowbase + r;
      f16x8 v0 = *(const f16x8*)(ldso + r*72 + q*16);
      f16x8 v1 = *(const f16x8*)(ldso + r*72 + q*16 + 8);
      *(f16x8*)(zout + (size_t)p*64 + q*16) = v0;
      *(f16x8*)(zout + (size_t)p*64 + q*16 + 8) = v1;
    }
    __syncthreads();
  }
  #pragma unroll
  for (int nt = 0; nt < 4; nt++) {
    float v, w;
    v = s0sum[nt]; v += __shfl_xor(v,16); v += __shfl_xor(v,32);
    w = s0sq[nt];  w += __shfl_xor(w,16); w += __shfl_xor(w,32);
    if (lane < 16) { atomicAdd(&sstat[0][nt*16+lane][0], v); atomicAdd(&sstat[0][nt*16+lane][1], w); }
    v = s1sum[nt]; v += __shfl_xor(v,16); v += __shfl_xor(v,32);
    w = s1sq[nt];  w += __shfl_xor(w,16); w += __shfl_xor(w,32);
    if (lane < 16) { atomicAdd(&sstat[1][nt*16+lane][0], v); atomicAdd(&sstat[1][nt*16+lane][1], w); }
  }
  __syncthreads();
  {
    float v = ((float*)sstat)[tid];
    if (v != 0.f) atomicAdd(&outstats[tid], v);
  }
}

// ---------------- final BN + relu + att + destination-sorted segment sum ----------------
__global__ __launch_bounds__(256) void k_scatter(
    const f16* __restrict__ z3, const float* __restrict__ att,
    const float* __restrict__ bngp, const float* __restrict__ bnbp,
    const float* __restrict__ instats, const int* __restrict__ sc,
    const int* __restrict__ start, const int* __restrict__ dperm,
    float* __restrict__ outt, f16* __restrict__ nfh)
{
  __shared__ float lscale[2][64], lshift[2][64];
  int tid = threadIdx.x;
  int c0p = sc[5];
  {
    int c0 = sc[4], c1 = sc[6];
    if (tid < 128) {
      int b = tid>>6, n = tid&63;
      int cb = b ? c1 : c0; if (cb < 1) cb = 1;
      float inv = 1.f/(float)cb;
      float s = instats[(b*64+n)*2], sq = instats[(b*64+n)*2+1];
      float mean = s*inv, var = sq*inv - mean*mean;
      float rstd = rsqrtf(var + EPSF);
      float scl = bngp[b*256+n]*rstd;
      lscale[b][n] = scl;
      lshift[b][n] = bnbp[b*256+n] - mean*scl;
    }
  }
  __syncthreads();
  int gid = blockIdx.x*256 + tid;
  int n = gid >> 3, q = gid & 7;
  if (n >= NN) return;
  int s = start[n];
  int e = start[n+1];
  float a0 = att[0], a1 = att[1];
  float acc[8] = {0,0,0,0,0,0,0,0};
  float sc0[8], sh0[8], sc1[8], sh1[8];
  #pragma unroll
  for (int j2 = 0; j2 < 8; j2++) {
    int f = q*8 + j2;
    sc0[j2] = lscale[0][f]; sh0[j2] = lshift[0][f];
    sc1[j2] = lscale[1][f]; sh1[j2] = lshift[1][f];
  }
  for (int t = s; t < e; t++) {
    int p = dperm[t];
    int b = (p >= c0p) ? 1 : 0;
    float a = b ? a1 : a0;
    f16x8 raw = *(const f16x8*)(z3 + (size_t)p*64 + q*8);
    #pragma unroll
    for (int j2 = 0; j2 < 8; j2++) {
      float x = (float)raw[j2]*(b ? sc1[j2] : sc0[j2]) + (b ? sh1[j2] : sh0[j2]);
      acc[j2] += fmaxf(x, 0.f) * a;   // leaky_relu identity for x>=0
    }
  }
  float4 lo, hi;
  lo.x=acc[0]; lo.y=acc[1]; lo.z=acc[2]; lo.w=acc[3];
  hi.x=acc[4]; hi.y=acc[5]; hi.z=acc[6]; hi.w=acc[7];
  *(float4*)(outt + (size_t)n*64 + q*8) = lo;
  *(float4*)(outt + (size_t)n*64 + q*8 + 4) = hi;
  f16x8 h;
  #pragma unroll
  for (int j2 = 0; j2 < 8; j2++) h[j2] = (f16)acc[j2];
  *(f16x8*)(nfh + (size_t)n*64 + q*8) = h;
}

extern "C" void kernel_launch(void* const* d_in, const int* in_sizes, int n_in,
                              void* d_out, int out_size, void* d_ws, size_t ws_size,
                              hipStream_t stream)
{
  const float* input_feature = (const float*)d_in[0];
  const float* coords   = (const float*)d_in[1];
  const float* face_x   = (const float*)d_in[3];
  const float* att      = (const float*)d_in[4];
  const float* W_geo    = (const float*)d_in[5];
  const float* b_geo    = (const float*)d_in[6];
  const float* g_geo    = (const float*)d_in[7];
  const float* be_geo   = (const float*)d_in[8];
  const float* spnn_W0  = (const float*)d_in[9];
  const float* spnn_b0  = (const float*)d_in[10];
  const float* spnn_Wr  = (const float*)d_in[11];
  const float* spnn_br  = (const float*)d_in[12];
  const float* bn_g     = (const float*)d_in[13];
  const float* bn_b     = (const float*)d_in[14];
  const int* ewf  = (const int*)d_in[15];
  const int* eidx = (const int*)d_in[16];
  const int* exjk = (const int*)d_in[17];
  const int* exij = (const int*)d_in[18];
  float* out = (float*)d_out;
  char* ws = (char*)d_ws;

  size_t off = 0;
  auto take = [&](size_t bytes) -> char* {
    size_t o = off; off = (off + bytes + 255) & ~(size_t)255; return ws + o;
  };
  int*   sc     = (int*)take(256);
  float* stats  = (float*)take(13*256*sizeof(float));  // geo + 3*4 layer stat buffers, each [2][64][2]
  int*   cnt    = (int*)take(sizeof(int)*NN);
  int*   startn = (int*)take(sizeof(int)*(NN+1));
  int*   curn   = (int*)take(sizeof(int)*NN);
  int*   btot   = (int*)take(sizeof(int)*256);
  int*   dperm  = (int*)take(sizeof(int)*EPAD);
  unsigned char* biedge = (unsigned char*)take(E_TRIP);
  int* epos = (int*)take(sizeof(int)*EPAD);
  int* ip   = (int*)take(sizeof(int)*EPAD);
  int* jp   = (int*)take(sizeof(int)*EPAD);
  int* kp   = (int*)take(sizeof(int)*EPAD);
  f16* W0h  = (f16*)take(sizeof(f16)*3*2*64*256);
  f16* Wrh  = (f16*)take(sizeof(f16)*3*2*3*64*64);
  f16* nf16 = (f16*)take(sizeof(f16)*(size_t)NN*64);
  f16* zgeo = (f16*)take(sizeof(f16)*(size_t)EPAD*64);
  f16* zA   = (f16*)take(sizeof(f16)*(size_t)EPAD*64);
  f16* zB   = (f16*)take(sizeof(f16)*(size_t)EPAD*64);
  if (off > ws_size) return;  // workspace insufficient; cannot run

  hipMemsetAsync(sc, 0, 256 + 13*256*sizeof(float), stream);
  hipMemsetAsync(cnt, 0, sizeof(int)*NN, stream);

  k_count    <<<1954, 256, 0, stream>>>(ewf, exij, exjk, biedge, sc);
  k_scal     <<<1, 1, 0, stream>>>(sc);
  k_partition<<<1954, 256, 0, stream>>>(biedge, eidx, sc, epos, ip, jp, kp);
  k_cvt      <<<25673, 256, 0, stream>>>(spnn_W0, spnn_Wr, input_feature, W0h, Wrh, nf16);
  // destination counting sort (i is the same for all 3 interactions)
  k_hist <<<1954, 256, 0, stream>>>(ip, sc, cnt);
  k_scan1<<<196, 512, 0, stream>>>(cnt, startn, btot);
  k_scan2<<<1, 256, 0, stream>>>(btot);
  k_scan3<<<196, 512, 0, stream>>>(startn, curn, btot, sc);
  k_place<<<1954, 256, 0, stream>>>(ip, sc, curn, dperm);

  k_geo      <<<NBLK256, 256, 0, stream>>>(coords, face_x, ewf, exij, exjk, W_geo, b_geo,
                                           sc, epos, ip, jp, kp, zgeo, stats);
  for (int t = 0; t < 3; t++) {
    float* outt = out + (size_t)t*NN*64;
    k_layer0<<<1024, 256, 0, stream>>>(nf16, zgeo,
        W0h + (size_t)t*2*64*256, spnn_b0 + t*2*64,
        g_geo, be_geo, stats, stats + (size_t)(1 + t*4)*256,
        sc, ip, jp, kp, zA);
    f16* zi = zA; f16* zo = zB;
    for (int h = 0; h < 3; h++) {
      k_hidden<<<1024, 256, 0, stream>>>(zi, zo,
          Wrh + (size_t)t*2*3*64*64 + (size_t)h*64*64,
          spnn_br + t*2*3*64 + h*64,
          bn_g + t*2*4*64 + h*64,
          bn_b + t*2*4*64 + h*64,
          stats + (size_t)(1 + t*4 + h)*256,
          stats + (size_t)(1 + t*4 + h + 1)*256,
          sc);
      f16* tmp = zi; zi = zo; zo = tmp;
    }
    k_scatter<<<(NN*8 + 255)/256, 256, 0, stream>>>(zi, att,
        bn_g + t*2*4*64 + 3*64, bn_b + t*2*4*64 + 3*64,
        stats + (size_t)(1 + t*4 + 3)*256, sc, startn, dperm, outt, nf16);
  }
}